// Round 9
// baseline (366.041 us; speedup 1.0000x reference)
//
#include <hip/hip_runtime.h>

// LSTM (B=2048, T=168, I=6, H=128) + FC(128->64, PReLU) + FC(64->1, PReLU).
// V9: TWO-GROUP SOFTWARE PIPELINE (breaks the per-step latency chain R5-R8
// were stuck on). Block owns 8 rows = G0 (0-3) + G1 (4-7), each with its own
// 4-row A-buffer (K''=288 slot layout as V6-V8: h_hi[0,128) h_lo[128,256)
// x_hi[256,262) x_lo[262,268) bias@268).
// Per step: phase A = MFMA G0(s) || pointwise G1(s-1) || stage xG1(s); barrier;
//           phase B = MFMA G1(s) || pointwise G0(s)   || stage xG0(s+1); barrier.
// acc -> pointwise dependency gets a full phase of slack; barriers only drain
// DS ops (MFMA chains cross them in flight).
// 4-row A-tile => D row == batch row (reg index) in EVERY lane: lane holds all
// 4 gates x 4 rows of its channel; pointwise selects row l4 (12 cndmask),
// one c-state per lane per group. Numerics identical to V6/V7/V8.

typedef __attribute__((ext_vector_type(8))) short short8;
typedef __attribute__((ext_vector_type(4))) float f32x4;

#define BT 512
#define TS 168
#define HID 128
#define AROW 320          // A-buffer row stride in ushorts (640 B)
#define GBUF (4 * AROW)   // one group buffer: 4 rows
#define NNT 4             // 4 gate tiles per wave (nt == gate index)

__device__ __forceinline__ ushort bf_hi(float v) {
    return (ushort)(__float_as_uint(v) >> 16);
}
__device__ __forceinline__ ushort bf_lo(float v) {
    unsigned h = __float_as_uint(v) & 0xFFFF0000u;
    float l = v - __uint_as_float(h);
    return (ushort)(__float_as_uint(l) >> 16);
}
__device__ __forceinline__ float sigm_f(float x) {
    return __fdividef(1.f, 1.f + __expf(-x));
}
__device__ __forceinline__ float tanh_f(float x) {
    return 1.f - __fdividef(2.f, __expf(2.f * x) + 1.f);
}
// compile-time-indexed 4-way select (no dynamic vector index -> no scratch)
__device__ __forceinline__ float sel4(f32x4 v, int q) {
    float r = v[0];
    r = (q == 1) ? v[1] : r;
    r = (q == 2) ? v[2] : r;
    r = (q == 3) ? v[3] : r;
    return r;
}

__global__ __launch_bounds__(BT, 2) void lstm_mfma9_kernel(
    const float* __restrict__ s_inp,   // [2048,168,5]
    const float* __restrict__ flow_x,  // [2048,168,1]
    const float* __restrict__ W_ih,    // [512,6]
    const float* __restrict__ W_hh,    // [512,128]
    const float* __restrict__ b_ih,    // [512]
    const float* __restrict__ b_hh,    // [512]
    const float* __restrict__ W1,      // [64,128]
    const float* __restrict__ b1,      // [64]
    const float* __restrict__ a1p,     // [1]
    const float* __restrict__ W2,      // [1,64]
    const float* __restrict__ b2,      // [1]
    const float* __restrict__ a2p,     // [1]
    float* __restrict__ out)           // [2048]
{
    __shared__ float xs[8][TS][6];                    // 32256 B
    __shared__ __align__(16) ushort hA[2 * GBUF];     // 5120 B (G0 | G1)
    __shared__ float y1s[8][64];                      // 2048 B

    const int t = threadIdx.x;
    const int w = t >> 6;       // wave 0..7
    const int l = t & 63;
    const int l15 = l & 15;
    const int l4 = l >> 4;      // 0..3
    const int row_base = blockIdx.x * 8;

    // ---- register-resident B fragments (hi/lo planes), same as V6-V8 ----
    // q: 0-3 <-> kk 0-3 (reused for kk 4-7 pairing h_lo), 4 <-> kk 8 (x/bias).
    short8 P1s[5][NNT], P2s[5][NNT];
    #pragma unroll
    for (int nt = 0; nt < NNT; ++nt) {
        const int gc = nt * HID + w * 16 + l15;   // gate nt, channel w*16+l15
        const float bias = b_ih[gc] + b_hh[gc];
        #pragma unroll
        for (int q = 0; q < 4; ++q) {
            #pragma unroll
            for (int j = 0; j < 8; ++j) {
                float v = W_hh[gc * HID + q * 32 + l4 * 8 + j];
                P1s[q][nt][j] = (short)bf_hi(v);
                P2s[q][nt][j] = (short)bf_lo(v);
            }
        }
        #pragma unroll
        for (int j = 0; j < 8; ++j) {
            int u = l4 * 8 + j;   // slot 256+u
            float v = (u < 6)  ? W_ih[gc * 6 + u]
                    : (u < 12) ? W_ih[gc * 6 + (u - 6)]
                    : (u == 12) ? bias : 0.f;
            P1s[4][nt][j] = (short)bf_hi(v);
            P2s[4][nt][j] = (short)bf_lo(v);
        }
    }

    // ---- stage x for this block's 8 rows into LDS (coalesced) ----
    for (int idx = t; idx < 8 * TS * 5; idx += BT) {
        int r = idx / (TS * 5), rem = idx % (TS * 5);
        xs[r][rem / 5][rem % 5] = s_inp[(size_t)row_base * (TS * 5) + idx];
    }
    for (int idx = t; idx < 8 * TS; idx += BT) {
        xs[idx / TS][idx % TS][5] = flow_x[(size_t)row_base * TS + idx];
    }
    // zero both A buffers
    for (int idx = t; idx < 2 * GBUF / 2; idx += BT)
        ((unsigned*)hA)[idx] = 0u;
    __syncthreads();

    // bias column (slot 268) = 1.0, rows 0-3 of both buffers
    if (t < 8) {
        int b = t >> 2, r = t & 3;
        int byte = (2 * 268) ^ (r << 4);
        hA[b * GBUF + r * AROW + (byte >> 1)] = 0x3F80;
    }
    // x(0) for all 8 rows into the right buffer: t<48 hi plane, t in [64,112) lo
    {
        const bool ih = (t < 48);
        const bool il = (t >= 64 && t < 112);
        if (ih | il) {
            int xu = ih ? t : (t - 64);
            int xr = xu / 6, xi = xu % 6;          // global row 0..7
            int b = xr >> 2, lr = xr & 3;
            int slot = ih ? (256 + xi) : (262 + xi);
            int idx = b * GBUF + lr * AROW + ((((2 * slot) ^ (lr << 4))) >> 1);
            float v = xs[xr][0][xi];
            hA[idx] = ih ? bf_hi(v) : bf_lo(v);
        }
    }

    // ---- per-step constants ----
    const int arow = l15 & 3;                 // physical A row (l15>=4 broadcast)
    const int a_base = arow * AROW;
    const int a_swz = arow << 4;
    const int ch = w * 16 + l15;              // this lane's channel
    // pointwise: lane owns row l4 of its group; h write offset within buffer:
    const int hw = l4 * AROW + ((((2 * ch) ^ (l4 << 4))) >> 1);  // h_hi; +128 = h_lo
    // in-loop x stagers: 24 hi + 24 lo threads, local rows 0-3
    const bool sxh = (t < 24);
    const bool sxl = (t >= 64 && t < 88);
    const int sxu = sxh ? t : (t - 64);
    const int sxr = (sxu < 24) ? (sxu / 6) : 0;     // local row 0..3
    const int sxi = (sxu < 24) ? (sxu % 6) : 0;
    const int sxslot = sxh ? (256 + sxi) : (262 + sxi);
    const int sxw = sxr * AROW + ((((2 * sxslot) ^ (sxr << 4))) >> 1);

    float cG0 = 0.f, cG1 = 0.f, hG0 = 0.f, hG1 = 0.f;
    f32x4 accA[NNT], accB[NNT];
    #pragma unroll
    for (int nt = 0; nt < NNT; ++nt) {
        accA[nt] = (f32x4){0.f, 0.f, 0.f, 0.f};
        accB[nt] = (f32x4){0.f, 0.f, 0.f, 0.f};
    }

    for (int s = 0; s < TS; ++s) {
        __syncthreads();  // G0buf (h(s-1), x(s)) ready; accB(G1,s-1) in regs

        // ---- phase A: MFMA G0(s) ----
        #pragma unroll
        for (int nt = 0; nt < NNT; ++nt) accA[nt] = (f32x4){0.f, 0.f, 0.f, 0.f};
        #pragma unroll
        for (int kk = 0; kk < 9; ++kk) {
            const int q = (kk < 4) ? kk : ((kk < 8) ? kk - 4 : 4);
            int off = ((kk * 64 + l4 * 16) ^ a_swz) >> 1;
            short8 a = *(const short8*)(hA + a_base + off);
            #pragma unroll
            for (int nt = 0; nt < NNT; ++nt)
                accA[nt] = __builtin_amdgcn_mfma_f32_16x16x32_bf16(a, P1s[q][nt], accA[nt], 0, 0, 0);
            if (kk < 4 || kk == 8) {
                #pragma unroll
                for (int nt = 0; nt < NNT; ++nt)
                    accA[nt] = __builtin_amdgcn_mfma_f32_16x16x32_bf16(a, P2s[q][nt], accA[nt], 0, 0, 0);
            }
        }
        // pointwise G1(s-1) from accB (full-phase-old -> chain drained)
        if (s > 0) {
            float gi = sel4(accB[0], l4), gf = sel4(accB[1], l4);
            float gg = sel4(accB[2], l4), go = sel4(accB[3], l4);
            float ia = sigm_f(gi), fa = sigm_f(gf), ga = tanh_f(gg), oa = sigm_f(go);
            cG1 = fa * cG1 + ia * ga;
            hG1 = oa * tanh_f(cG1);
            hA[GBUF + hw] = bf_hi(hG1);
            hA[GBUF + hw + 128] = bf_lo(hG1);
        }
        // stage xG1(s)
        if (sxh | sxl) {
            float v = xs[4 + sxr][s][sxi];
            hA[GBUF + sxw] = sxh ? bf_hi(v) : bf_lo(v);
        }

        __syncthreads();  // G1buf (h(s-1), x(s)) ready; accA(G0,s) in flight

        // ---- phase B: MFMA G1(s) ----
        #pragma unroll
        for (int nt = 0; nt < NNT; ++nt) accB[nt] = (f32x4){0.f, 0.f, 0.f, 0.f};
        #pragma unroll
        for (int kk = 0; kk < 9; ++kk) {
            const int q = (kk < 4) ? kk : ((kk < 8) ? kk - 4 : 4);
            int off = ((kk * 64 + l4 * 16) ^ a_swz) >> 1;
            short8 a = *(const short8*)(hA + GBUF + a_base + off);
            #pragma unroll
            for (int nt = 0; nt < NNT; ++nt)
                accB[nt] = __builtin_amdgcn_mfma_f32_16x16x32_bf16(a, P1s[q][nt], accB[nt], 0, 0, 0);
            if (kk < 4 || kk == 8) {
                #pragma unroll
                for (int nt = 0; nt < NNT; ++nt)
                    accB[nt] = __builtin_amdgcn_mfma_f32_16x16x32_bf16(a, P2s[q][nt], accB[nt], 0, 0, 0);
            }
        }
        // pointwise G0(s) from accA (one barrier of slack)
        {
            float gi = sel4(accA[0], l4), gf = sel4(accA[1], l4);
            float gg = sel4(accA[2], l4), go = sel4(accA[3], l4);
            float ia = sigm_f(gi), fa = sigm_f(gf), ga = tanh_f(gg), oa = sigm_f(go);
            cG0 = fa * cG0 + ia * ga;
            hG0 = oa * tanh_f(cG0);
            hA[hw] = bf_hi(hG0);
            hA[hw + 128] = bf_lo(hG0);
        }
        // stage xG0(s+1)
        if ((sxh | sxl) && s + 1 < TS) {
            float v = xs[sxr][s + 1][sxi];
            hA[sxw] = sxh ? bf_hi(v) : bf_lo(v);
        }
    }

    // epilogue: final G1 pointwise (step 167) — no LDS write needed
    {
        float gi = sel4(accB[0], l4), gf = sel4(accB[1], l4);
        float gg = sel4(accB[2], l4), go = sel4(accB[3], l4);
        float ia = sigm_f(gi), fa = sigm_f(gf), ga = tanh_f(gg), oa = sigm_f(go);
        cG1 = fa * cG1 + ia * ga;
        hG1 = oa * tanh_f(cG1);
    }

    // ---- FC head ----
    // all xs reads completed before the last mid-loop barrier; safe to reuse
    float* hfin = (float*)xs;  // [8][128] f32
    hfin[l4 * HID + ch] = hG0;          // G0: global rows 0-3
    hfin[(4 + l4) * HID + ch] = hG1;    // G1: global rows 4-7
    __syncthreads();

    {
        int r = t >> 6, j = t & 63;
        const float4* wrow = (const float4*)(W1 + j * HID);
        const float4* hr = (const float4*)(hfin + r * HID);
        float acc = b1[j];
        #pragma unroll
        for (int q = 0; q < HID / 4; ++q) {
            float4 a = hr[q], b = wrow[q];
            acc += a.x * b.x + a.y * b.y + a.z * b.z + a.w * b.w;
        }
        float av = a1p[0];
        y1s[r][j] = (acc >= 0.f) ? acc : av * acc;
    }
    __syncthreads();

    if (t < 8) {
        const float4* w2 = (const float4*)W2;
        const float4* yr = (const float4*)&y1s[t][0];
        float acc = 0.f;
        #pragma unroll
        for (int q = 0; q < 64 / 4; ++q) {
            float4 a = yr[q], b = w2[q];
            acc += a.x * b.x + a.y * b.y + a.z * b.z + a.w * b.w;
        }
        acc += b2[0];
        float av = a2p[0];
        out[row_base + t] = (acc >= 0.f) ? acc : av * acc;
    }
}

extern "C" void kernel_launch(void* const* d_in, const int* in_sizes, int n_in,
                              void* d_out, int out_size, void* d_ws, size_t ws_size,
                              hipStream_t stream) {
    const float* s_inp  = (const float*)d_in[0];
    const float* flow_x = (const float*)d_in[1];
    const float* W_ih   = (const float*)d_in[2];
    const float* W_hh   = (const float*)d_in[3];
    const float* b_ih   = (const float*)d_in[4];
    const float* b_hh   = (const float*)d_in[5];
    const float* W1     = (const float*)d_in[6];
    const float* b1     = (const float*)d_in[7];
    const float* a1     = (const float*)d_in[8];
    const float* W2     = (const float*)d_in[9];
    const float* b2     = (const float*)d_in[10];
    const float* a2     = (const float*)d_in[11];
    float* out = (float*)d_out;

    dim3 grid(2048 / 8);   // 256 blocks, 8 rows each -> 1 block/CU
    dim3 block(BT);
    lstm_mfma9_kernel<<<grid, block, 0, stream>>>(
        s_inp, flow_x, W_ih, W_hh, b_ih, b_hh, W1, b1, a1, W2, b2, a2, out);
}

// Round 10
// 334.678 us; speedup vs baseline: 1.0937x; 1.0937x over previous
//
#include <hip/hip_runtime.h>

// LSTM (B=2048, T=168, I=6, H=128) + FC(128->64, PReLU) + FC(64->1, PReLU).
// V10: OCCUPANCY FIX — 16 waves/block (4/SIMD) via OPERAND SWAP.
// R8/R9 showed ~18 cyc MFMA-pipe busy per MFMA (vs 4.85 issue) at 2 waves/SIMD:
// dependent-chain latency unhidden. 128 VGPR allows 16 waves/CU; launch them.
// Weights are now the MFMA A-operand: A-tile rows = 4 channels x 4 gates
// (row = ch_local*4 + gate), h is the B-operand (same LDS layout/read pattern
// as V8). Lane's 4 D-regs = gates i,f,g,o of (channel w*8+nt*4+l4, batch row
// l15&7) -> pointwise fully in-register. 28 MFMA/wave/step, 112/SIMD (= V8
// total). Double-buffered h array, 1 barrier/step. Numerics identical to V8.

typedef __attribute__((ext_vector_type(8))) short short8;
typedef __attribute__((ext_vector_type(4))) float f32x4;

#define BT 1024
#define TS 168
#define HID 128
#define AROW 320          // h-array row stride in ushorts (640 B)
#define ABUF (8 * AROW)   // one buffer: 8 rows
#define NNT 2             // 2 A-tiles per wave (8 channels)

__device__ __forceinline__ ushort bf_hi(float v) {
    return (ushort)(__float_as_uint(v) >> 16);
}
__device__ __forceinline__ ushort bf_lo(float v) {
    unsigned h = __float_as_uint(v) & 0xFFFF0000u;
    float l = v - __uint_as_float(h);
    return (ushort)(__float_as_uint(l) >> 16);
}
__device__ __forceinline__ float sigm_f(float x) {
    return __fdividef(1.f, 1.f + __expf(-x));
}
__device__ __forceinline__ float tanh_f(float x) {
    return 1.f - __fdividef(2.f, __expf(2.f * x) + 1.f);
}

__global__ __launch_bounds__(BT, 4) void lstm_mfma10_kernel(
    const float* __restrict__ s_inp,   // [2048,168,5]
    const float* __restrict__ flow_x,  // [2048,168,1]
    const float* __restrict__ W_ih,    // [512,6]
    const float* __restrict__ W_hh,    // [512,128]
    const float* __restrict__ b_ih,    // [512]
    const float* __restrict__ b_hh,    // [512]
    const float* __restrict__ W1,      // [64,128]
    const float* __restrict__ b1,      // [64]
    const float* __restrict__ a1p,     // [1]
    const float* __restrict__ W2,      // [1,64]
    const float* __restrict__ b2,      // [1]
    const float* __restrict__ a2p,     // [1]
    float* __restrict__ out)           // [2048]
{
    __shared__ float xs[8][TS][6];                    // 32256 B
    __shared__ __align__(16) ushort hA[2 * ABUF];     // 10240 B (double buffer)
    __shared__ float y1s[8][64];                      // 2048 B

    const int t = threadIdx.x;
    const int w = t >> 6;       // wave 0..15
    const int l = t & 63;
    const int l15 = l & 15;
    const int l4 = l >> 4;      // 0..3
    const int row_base = blockIdx.x * 8;

    // ---- register-resident WEIGHT fragments as the A-operand ----
    // Lane holds A[m = l15][k = kk*32 + l4*8 + j] for tile nt.
    // A-row m: gate = m&3, channel = w*8 + nt*4 + (m>>2).
    // K slots (same as V6-V9): [0,128) h_hi x W_hi | kk4-7 pair h_lo x W_hi |
    // kk8: u<6 x_hi*Wih_hi, u in[6,12) x_lo*Wih_hi(P1), u==12 bias*1.0.
    // P2 plane: W_lo (ah*bl) for kk0-3, x*Wih_lo at kk8.
    short8 P1s[5][NNT], P2s[5][NNT];
    #pragma unroll
    for (int nt = 0; nt < NNT; ++nt) {
        const int wrow = (l15 & 3) * HID + w * 8 + nt * 4 + (l15 >> 2);
        const float bias = b_ih[wrow] + b_hh[wrow];
        #pragma unroll
        for (int q = 0; q < 4; ++q) {
            #pragma unroll
            for (int j = 0; j < 8; ++j) {
                float v = W_hh[wrow * HID + q * 32 + l4 * 8 + j];
                P1s[q][nt][j] = (short)bf_hi(v);
                P2s[q][nt][j] = (short)bf_lo(v);
            }
        }
        #pragma unroll
        for (int j = 0; j < 8; ++j) {
            int u = l4 * 8 + j;   // slot 256+u
            float v = (u < 6)  ? W_ih[wrow * 6 + u]
                    : (u < 12) ? W_ih[wrow * 6 + (u - 6)]
                    : (u == 12) ? bias : 0.f;
            P1s[4][nt][j] = (short)bf_hi(v);
            P2s[4][nt][j] = (short)bf_lo(v);
        }
    }

    // ---- stage x for this block's 8 rows into LDS (coalesced) ----
    for (int idx = t; idx < 8 * TS * 5; idx += BT) {
        int r = idx / (TS * 5), rem = idx % (TS * 5);
        xs[r][rem / 5][rem % 5] = s_inp[(size_t)row_base * (TS * 5) + idx];
    }
    for (int idx = t; idx < 8 * TS; idx += BT) {
        xs[idx / TS][idx % TS][5] = flow_x[(size_t)row_base * TS + idx];
    }
    // zero BOTH h buffers
    for (int idx = t; idx < ABUF; idx += BT)   // 2*ABUF ushorts = ABUF u32
        ((unsigned*)hA)[idx] = 0u;
    __syncthreads();

    // bias column (slot 268) = 1.0 in all 8 rows of BOTH buffers
    if (t < 16) {
        int b = t >> 3, r = t & 7;
        int byte = (2 * 268) ^ (r << 4);
        hA[b * ABUF + r * AROW + (byte >> 1)] = 0x3F80;
    }
    // x(0) into buffer 0: t<48 hi plane (slots 256+i), t in [64,112) lo (262+i)
    const bool xhi = (t < 48);
    const bool xlo = (t >= 64 && t < 112);
    const int xu = xhi ? t : (t - 64);
    const int xr = (xu < 48) ? (xu / 6) : 0;
    const int xi = (xu < 48) ? (xu % 6) : 0;
    const int xslot = xhi ? (256 + xi) : (262 + xi);
    const int xw_idx = xr * AROW + ((((2 * xslot) ^ ((xr & 7) << 4))) >> 1);
    if (xhi | xlo) {
        float v = xs[xr][0][xi];
        hA[xw_idx] = xhi ? bf_hi(v) : bf_lo(v);
    }

    // ---- per-step constants ----
    const int arow = l15 & 7;                 // batch row this lane consumes
    const int a_base = arow * AROW;
    const int a_swz = arow << 4;
    const int ch0 = w * 8 + l4;               // nt=0 channel
    const int ch1 = w * 8 + 4 + l4;           // nt=1 channel
    const bool wr_en = (l15 < 8);             // lanes l15>=8 are duplicates
    const int hw0 = arow * AROW + ((((2 * ch0) ^ (arow << 4))) >> 1);  // h_hi; +128 lo
    const int hw1 = arow * AROW + ((((2 * ch1) ^ (arow << 4))) >> 1);

    float c0 = 0.f, c1 = 0.f, h0f = 0.f, h1f = 0.f;
    int rb = 0, wbo = ABUF;

    for (int s = 0; s < TS; ++s) {
        __syncthreads();  // writes to buf[rb] (h(s-1), x(s)) visible

        f32x4 acc0 = (f32x4){0.f, 0.f, 0.f, 0.f};
        f32x4 acc1 = (f32x4){0.f, 0.f, 0.f, 0.f};

        #pragma unroll
        for (int kk = 0; kk < 9; ++kk) {
            const int q = (kk < 4) ? kk : ((kk < 8) ? kk - 4 : 4);
            int off = ((kk * 64 + l4 * 16) ^ a_swz) >> 1;  // ushort units
            short8 b = *(const short8*)(hA + rb + a_base + off);
            acc0 = __builtin_amdgcn_mfma_f32_16x16x32_bf16(P1s[q][0], b, acc0, 0, 0, 0);
            acc1 = __builtin_amdgcn_mfma_f32_16x16x32_bf16(P1s[q][1], b, acc1, 0, 0, 0);
            if (kk < 4 || kk == 8) {
                acc0 = __builtin_amdgcn_mfma_f32_16x16x32_bf16(P2s[q][0], b, acc0, 0, 0, 0);
                acc1 = __builtin_amdgcn_mfma_f32_16x16x32_bf16(P2s[q][1], b, acc1, 0, 0, 0);
            }
        }

        // stage x(s+1) into the WRITE buffer
        if ((xhi | xlo) && s + 1 < TS) {
            float v = xs[xr][s + 1][xi];
            hA[wbo + xw_idx] = xhi ? bf_hi(v) : bf_lo(v);
        }

        // pointwise: lane's 4 regs = gates i,f,g,o of (ch, batch row arow)
        {
            float ia = sigm_f(acc0[0]);
            float fa = sigm_f(acc0[1]);
            float ga = tanh_f(acc0[2]);
            float oa = sigm_f(acc0[3]);
            c0 = fa * c0 + ia * ga;
            h0f = oa * tanh_f(c0);
            if (wr_en) {
                hA[wbo + hw0] = bf_hi(h0f);
                hA[wbo + hw0 + 128] = bf_lo(h0f);
            }
        }
        {
            float ia = sigm_f(acc1[0]);
            float fa = sigm_f(acc1[1]);
            float ga = tanh_f(acc1[2]);
            float oa = sigm_f(acc1[3]);
            c1 = fa * c1 + ia * ga;
            h1f = oa * tanh_f(c1);
            if (wr_en) {
                hA[wbo + hw1] = bf_hi(h1f);
                hA[wbo + hw1 + 128] = bf_lo(h1f);
            }
        }

        int tmp = rb; rb = wbo; wbo = tmp;
    }
    __syncthreads();  // all xs reads done

    // ---- FC head ----
    float* hfin = (float*)xs;  // reuse xs as [8][128] f32
    if (wr_en) {
        hfin[arow * HID + ch0] = h0f;
        hfin[arow * HID + ch1] = h1f;
    }
    __syncthreads();

    if (t < 512) {
        int r = t >> 6, j = t & 63;
        const float4* wrow = (const float4*)(W1 + j * HID);
        const float4* hr = (const float4*)(hfin + r * HID);
        float acc = b1[j];
        #pragma unroll
        for (int q = 0; q < HID / 4; ++q) {
            float4 a = hr[q], b = wrow[q];
            acc += a.x * b.x + a.y * b.y + a.z * b.z + a.w * b.w;
        }
        float av = a1p[0];
        y1s[r][j] = (acc >= 0.f) ? acc : av * acc;
    }
    __syncthreads();

    if (t < 8) {
        const float4* w2 = (const float4*)W2;
        const float4* yr = (const float4*)&y1s[t][0];
        float acc = 0.f;
        #pragma unroll
        for (int q = 0; q < 64 / 4; ++q) {
            float4 a = yr[q], b = w2[q];
            acc += a.x * b.x + a.y * b.y + a.z * b.z + a.w * b.w;
        }
        acc += b2[0];
        float av = a2p[0];
        out[row_base + t] = (acc >= 0.f) ? acc : av * acc;
    }
}

extern "C" void kernel_launch(void* const* d_in, const int* in_sizes, int n_in,
                              void* d_out, int out_size, void* d_ws, size_t ws_size,
                              hipStream_t stream) {
    const float* s_inp  = (const float*)d_in[0];
    const float* flow_x = (const float*)d_in[1];
    const float* W_ih   = (const float*)d_in[2];
    const float* W_hh   = (const float*)d_in[3];
    const float* b_ih   = (const float*)d_in[4];
    const float* b_hh   = (const float*)d_in[5];
    const float* W1     = (const float*)d_in[6];
    const float* b1     = (const float*)d_in[7];
    const float* a1     = (const float*)d_in[8];
    const float* W2     = (const float*)d_in[9];
    const float* b2     = (const float*)d_in[10];
    const float* a2     = (const float*)d_in[11];
    float* out = (float*)d_out;

    dim3 grid(2048 / 8);   // 256 blocks, 8 rows each -> 1 block/CU
    dim3 block(BT);        // 1024 threads = 16 waves = 4 waves/SIMD
    lstm_mfma10_kernel<<<grid, block, 0, stream>>>(
        s_inp, flow_x, W_ih, W_hh, b_ih, b_hh, W1, b1, a1, W2, b2, a2, out);
}

// Round 11
// 265.686 us; speedup vs baseline: 1.3777x; 1.2597x over previous
//
#include <hip/hip_runtime.h>

// LSTM (B=2048, T=168, I=6, H=128) + FC(128->64, PReLU) + FC(64->1, PReLU).
// V11 = V8 EXACTLY, except MFMAs are inline asm with "v" register constraints.
// Rationale (R5-R10 post-mortem): weight fragments (160 regs) exceed the 128
// arch-VGPRs the compiler was allocating; overflow went to AGPRs (V10: scratch),
// and per-MFMA v_accvgpr_read copies were the hidden VALU cost that kept every
// structural variant flat at ~253-334 us (VALUBusy 50-71%). Inline asm "v"
// constraints force weights + acc into arch VGPRs (~230 <= 256 at 2 waves/EU):
// zero accvgpr moves, zero scratch. Numerics bit-identical to V8.

typedef __attribute__((ext_vector_type(8))) short short8;
typedef __attribute__((ext_vector_type(4))) float f32x4;

#define BT 512
#define TS 168
#define HID 128
#define AROW 320          // A-array row stride in ushorts (640 B)
#define ABUF (8 * AROW)   // one buffer: 8 rows = 2560 ushorts
#define NNT 4             // 4 gate tiles per wave

// MFMA via inline asm: D=C=acc ("+v"), A=va, B=vb all in arch VGPRs.
#define MFMA_BF16(acc, va, vb) \
    asm("v_mfma_f32_16x16x32_bf16 %0, %1, %2, %0" : "+v"(acc) : "v"(va), "v"(vb))

__device__ __forceinline__ ushort bf_hi(float v) {
    return (ushort)(__float_as_uint(v) >> 16);
}
__device__ __forceinline__ ushort bf_lo(float v) {
    unsigned h = __float_as_uint(v) & 0xFFFF0000u;
    float l = v - __uint_as_float(h);
    return (ushort)(__float_as_uint(l) >> 16);
}
__device__ __forceinline__ float sigm_f(float x) {
    return __fdividef(1.f, 1.f + __expf(-x));
}
__device__ __forceinline__ float tanh_f(float x) {
    return 1.f - __fdividef(2.f, __expf(2.f * x) + 1.f);
}

__global__ __launch_bounds__(BT, 2) void lstm_mfma11_kernel(
    const float* __restrict__ s_inp,   // [2048,168,5]
    const float* __restrict__ flow_x,  // [2048,168,1]
    const float* __restrict__ W_ih,    // [512,6]
    const float* __restrict__ W_hh,    // [512,128]
    const float* __restrict__ b_ih,    // [512]
    const float* __restrict__ b_hh,    // [512]
    const float* __restrict__ W1,      // [64,128]
    const float* __restrict__ b1,      // [64]
    const float* __restrict__ a1p,     // [1]
    const float* __restrict__ W2,      // [1,64]
    const float* __restrict__ b2,      // [1]
    const float* __restrict__ a2p,     // [1]
    float* __restrict__ out)           // [2048]
{
    __shared__ float xs[8][TS][6];                      // 32256 B
    __shared__ __align__(16) ushort hA[2 * ABUF];       // 10240 B (double buffer)
    __shared__ float y1s[8][64];                        // 2048 B

    const int t = threadIdx.x;
    const int w = t >> 6;       // wave 0..7
    const int l = t & 63;
    const int l15 = l & 15;
    const int l4 = l >> 4;      // 0..3
    const int row_base = blockIdx.x * 8;

    // ---- register-resident B fragments (hi/lo bf16 planes) ----
    // storage q: 0-3 <-> kk 0-3 (reused for kk 4-7), 4 <-> kk 8.
    short8 P1s[5][NNT], P2s[5][NNT];
    #pragma unroll
    for (int nt = 0; nt < NNT; ++nt) {
        const int gc = nt * HID + w * 16 + l15;
        const float bias = b_ih[gc] + b_hh[gc];
        #pragma unroll
        for (int q = 0; q < 4; ++q) {
            #pragma unroll
            for (int j = 0; j < 8; ++j) {
                float v = W_hh[gc * HID + q * 32 + l4 * 8 + j];
                P1s[q][nt][j] = (short)bf_hi(v);
                P2s[q][nt][j] = (short)bf_lo(v);
            }
        }
        #pragma unroll
        for (int j = 0; j < 8; ++j) {
            int u = l4 * 8 + j;   // slot 256+u
            float v = (u < 6)  ? W_ih[gc * 6 + u]
                    : (u < 12) ? W_ih[gc * 6 + (u - 6)]
                    : (u == 12) ? bias : 0.f;
            P1s[4][nt][j] = (short)bf_hi(v);
            P2s[4][nt][j] = (short)bf_lo(v);
        }
    }

    // ---- stage x for this block's 8 rows into LDS (coalesced) ----
    for (int idx = t; idx < 8 * TS * 5; idx += BT) {
        int r = idx / (TS * 5), rem = idx % (TS * 5);
        xs[r][rem / 5][rem % 5] = s_inp[(size_t)row_base * (TS * 5) + idx];
    }
    for (int idx = t; idx < 8 * TS; idx += BT) {
        xs[idx / TS][idx % TS][5] = flow_x[(size_t)row_base * TS + idx];
    }
    // zero BOTH A buffers
    for (int idx = t; idx < 2 * ABUF / 2; idx += BT)
        ((unsigned*)hA)[idx] = 0u;
    __syncthreads();

    // bias column (slot 268) = 1.0 in all 8 rows of BOTH buffers
    if (t < 16) {
        int b = t >> 3, r = t & 7;
        int byte = (2 * 268) ^ (r << 4);
        hA[b * ABUF + r * AROW + (byte >> 1)] = 0x3F80;
    }
    // x(0) staging into buffer 0: threads 0-47 x_hi (slots 256+i), 64-111 x_lo (262+i)
    const bool xhi = (t < 48);
    const bool xlo = (t >= 64 && t < 112);
    const int xu = xhi ? t : (t - 64);
    const int xr = (xu < 48) ? (xu / 6) : 0;
    const int xi = (xu < 48) ? (xu % 6) : 0;
    const int xslot = xhi ? (256 + xi) : (262 + xi);
    const int xw_idx = xr * AROW + ((((2 * xslot) ^ ((xr & 7) << 4))) >> 1);
    if (xhi | xlo) {
        float v = xs[xr][0][xi];
        hA[xw_idx] = xhi ? bf_hi(v) : bf_lo(v);
    }

    // ---- per-step constants (offsets WITHIN a buffer) ----
    const int arow = l15 & 7;                       // physical A row (l15>=8 broadcasts)
    const int a_base = arow * AROW;
    const int a_swz = arow << 4;
    const int ch = w * 16 + l15;                    // this lane's channel
    const bool lowhalf = (l < 32);
    const int rbase = (l4 & 1) * 4 + (lowhalf ? 0 : 2);  // lane's 2 rows
    const int row0 = rbase, row1 = rbase + 1;
    const int hw0 = row0 * AROW + ((((2 * ch) ^ (row0 << 4))) >> 1);  // h_hi; +128 = h_lo
    const int hw1 = row1 * AROW + ((((2 * ch) ^ (row1 << 4))) >> 1);

    float c0 = 0.f, c1 = 0.f, h0f = 0.f, h1f = 0.f;
    int rb = 0, wbo = ABUF;   // read-buffer / write-buffer base offsets

    for (int s = 0; s < TS; ++s) {
        __syncthreads();  // all writes to buf[rb] (from step s-1) visible

        f32x4 acc[NNT];
        #pragma unroll
        for (int nt = 0; nt < NNT; ++nt) acc[nt] = (f32x4){0.f, 0.f, 0.f, 0.f};

        #pragma unroll
        for (int kk = 0; kk < 9; ++kk) {
            const int q = (kk < 4) ? kk : ((kk < 8) ? kk - 4 : 4);
            int off = ((kk * 64 + l4 * 16) ^ a_swz) >> 1;  // ushort units, 16B aligned
            short8 a = *(const short8*)(hA + rb + a_base + off);
            #pragma unroll
            for (int nt = 0; nt < NNT; ++nt)
                MFMA_BF16(acc[nt], a, P1s[q][nt]);
            if (kk < 4 || kk == 8) {
                #pragma unroll
                for (int nt = 0; nt < NNT; ++nt)
                    MFMA_BF16(acc[nt], a, P2s[q][nt]);
            }
        }

        // stage x(s+1) into the WRITE buffer (off the critical tail)
        if ((xhi | xlo) && s + 1 < TS) {
            float v = xs[xr][s + 1][xi];
            hA[wbo + xw_idx] = xhi ? bf_hi(v) : bf_lo(v);
        }

        // D row d holds batch row (d&7); lane picks its 2 rows directly
        float gi0 = lowhalf ? acc[0][0] : acc[0][2];
        float gf0 = lowhalf ? acc[1][0] : acc[1][2];
        float gg0 = lowhalf ? acc[2][0] : acc[2][2];
        float go0 = lowhalf ? acc[3][0] : acc[3][2];
        float gi1 = lowhalf ? acc[0][1] : acc[0][3];
        float gf1 = lowhalf ? acc[1][1] : acc[1][3];
        float gg1 = lowhalf ? acc[2][1] : acc[2][3];
        float go1 = lowhalf ? acc[3][1] : acc[3][3];

        // row0: activation + cell update + immediate h write
        {
            float ia = sigm_f(gi0);
            float fa = sigm_f(gf0);
            float ga = tanh_f(gg0);
            float oa = sigm_f(go0);
            c0 = fa * c0 + ia * ga;
            h0f = oa * tanh_f(c0);
            hA[wbo + hw0] = bf_hi(h0f);
            hA[wbo + hw0 + 128] = bf_lo(h0f);
        }
        // row1
        {
            float ia = sigm_f(gi1);
            float fa = sigm_f(gf1);
            float ga = tanh_f(gg1);
            float oa = sigm_f(go1);
            c1 = fa * c1 + ia * ga;
            h1f = oa * tanh_f(c1);
            hA[wbo + hw1] = bf_hi(h1f);
            hA[wbo + hw1 + 128] = bf_lo(h1f);
        }

        // swap buffers
        int tmp = rb; rb = wbo; wbo = tmp;
    }
    __syncthreads();  // all lanes done with xs

    // ---- FC head ----
    float* hfin = (float*)xs;  // reuse xs as [8][128] f32
    hfin[row0 * HID + ch] = h0f;
    hfin[row1 * HID + ch] = h1f;
    __syncthreads();

    {
        int r = t >> 6, j = t & 63;
        const float4* wrow = (const float4*)(W1 + j * HID);
        const float4* hr = (const float4*)(hfin + r * HID);
        float acc = b1[j];
        #pragma unroll
        for (int q = 0; q < HID / 4; ++q) {
            float4 a = hr[q], b = wrow[q];
            acc += a.x * b.x + a.y * b.y + a.z * b.z + a.w * b.w;
        }
        float av = a1p[0];
        y1s[r][j] = (acc >= 0.f) ? acc : av * acc;
    }
    __syncthreads();

    if (t < 8) {
        const float4* w2 = (const float4*)W2;
        const float4* yr = (const float4*)&y1s[t][0];
        float acc = 0.f;
        #pragma unroll
        for (int q = 0; q < 64 / 4; ++q) {
            float4 a = yr[q], b = w2[q];
            acc += a.x * b.x + a.y * b.y + a.z * b.z + a.w * b.w;
        }
        acc += b2[0];
        float av = a2p[0];
        out[row_base + t] = (acc >= 0.f) ? acc : av * acc;
    }
}

extern "C" void kernel_launch(void* const* d_in, const int* in_sizes, int n_in,
                              void* d_out, int out_size, void* d_ws, size_t ws_size,
                              hipStream_t stream) {
    const float* s_inp  = (const float*)d_in[0];
    const float* flow_x = (const float*)d_in[1];
    const float* W_ih   = (const float*)d_in[2];
    const float* W_hh   = (const float*)d_in[3];
    const float* b_ih   = (const float*)d_in[4];
    const float* b_hh   = (const float*)d_in[5];
    const float* W1     = (const float*)d_in[6];
    const float* b1     = (const float*)d_in[7];
    const float* a1     = (const float*)d_in[8];
    const float* W2     = (const float*)d_in[9];
    const float* b2     = (const float*)d_in[10];
    const float* a2     = (const float*)d_in[11];
    float* out = (float*)d_out;

    dim3 grid(2048 / 8);   // 256 blocks, 8 rows each -> 1 block/CU
    dim3 block(BT);
    lstm_mfma11_kernel<<<grid, block, 0, stream>>>(
        s_inp, flow_x, W_ih, W_hh, b_ih, b_hh, W1, b1, a1, W2, b2, a2, out);
}